// Round 7
// baseline (641.205 us; speedup 1.0000x reference)
//
#include <hip/hip_runtime.h>

typedef __attribute__((ext_vector_type(8))) short short8;
typedef __attribute__((ext_vector_type(4))) unsigned short ushort4v;
typedef __attribute__((ext_vector_type(4))) float f32x4;
typedef __attribute__((ext_vector_type(4))) unsigned int uint4v;

#define SCALE_F 0.17677669529663687f  // 1/sqrt(32)
#define SW(t) ((((t) ^ ((t) >> 3)) & 7) << 4)

__device__ __forceinline__ unsigned short f2bf(float f){
  unsigned u = __builtin_bit_cast(unsigned, f);
  u += 0x7fffu + ((u >> 16) & 1u);          // RNE
  return (unsigned short)(u >> 16);
}
__device__ __forceinline__ float bf2f(unsigned short h){
  unsigned u = ((unsigned)h) << 16;
  return __builtin_bit_cast(float, u);
}
__device__ __forceinline__ unsigned cvtpk(float a, float b){
  unsigned w;
  asm("v_cvt_pk_bf16_f32 %0, %1, %2" : "=v"(w) : "v"(a), "v"(b));
  return w;
}
__device__ __forceinline__ void st_pk4(void* p, f32x4 a){
  uint2 u; u.x = cvtpk(a[0], a[1]); u.y = cvtpk(a[2], a[3]);
  *(uint2*)p = u;
}

// One-time weight fp32 -> bf16 into workspace (both paths).
__global__ void prep_weights(const float* __restrict__ qw, const float* __restrict__ pw,
                             unsigned short* __restrict__ wsb)
{
  const int i = blockIdx.x * 256 + threadIdx.x;
  const int idx = i * 4;                        // 65536 elements total
  const float* src = (idx < 49152) ? (qw + idx) : (pw + (idx - 49152));
  f32x4 v = *(const f32x4*)src;
  ushort4v o;
  #pragma unroll
  for (int e = 0; e < 4; ++e) o[e] = f2bf(v[e]);
  *(ushort4v*)(wsb + idx) = o;
}

// ===========================================================================
// K1 v2: per-window fused, R2-proven layouts, merged phases (3 barriers/head)
// and write-contiguous scratch layout.
// LDS 39424 B -> 4 blocks/CU:
//   [    0,16384) : x bf16 [t=64][c=128] 256B rows swz SW(t); later attn-out
//   [16384,21504) : q_h bf16 [t=64][c=32] 80B rows
//   [21504,26624) : k_h bf16 [t=64][c=32] 80B rows
//   [26624,31232) : vT_h bf16 [c=32][t=64] 144B rows
//   [31232,39424) : S/P bf16 [64][64] 128B rows swz SW(row), softmax in-place
// Scratch: [win][mt=4][o=128][16 t] bf16 -> proj store = 512B contiguous/instr
// ===========================================================================
__global__ void __launch_bounds__(256, 4)
swin_k1(const float* __restrict__ x, const float* __restrict__ projb,
        const float* __restrict__ btab, const unsigned short* __restrict__ wbf,
        unsigned short* __restrict__ scr)
{
  __shared__ __align__(16) unsigned char sm[39424];
  unsigned char* const smq = sm + 16384;
  unsigned char* const smk = sm + 21504;
  unsigned char* const smv = sm + 26624;
  unsigned char* const smS = sm + 31232;

  const int tid  = threadIdx.x;
  const int lane = tid & 63, wv = tid >> 6;
  const int lr = lane & 15, lg = lane >> 4;

  const int bid = blockIdx.x;
  const int sw  = ((bid & 7) << 10) | (bid >> 3);
  const int b   = sw >> 10;
  const int wh  = (sw >> 5) & 31, ww = sw & 31;
  const int hb  = wh * 8 + 4, wb = ww * 8 + 4;
  const bool h31 = (wh == 31), w31 = (ww == 31);
  const int win = sw;

  // ---- hoisted proj weights + bias ----
  short8 BwH[2][4];
  float pbH[2];
  #pragma unroll
  for (int ntl = 0; ntl < 2; ++ntl) {
    const int o = (wv + 4 * ntl) * 16 + lr;
    pbH[ntl] = projb[o];
    #pragma unroll
    for (int kk = 0; kk < 4; ++kk)
      BwH[ntl][kk] = *(const short8*)(wbf + 49152 + o * 128 + kk * 32 + 8 * lg);
  }

  // ---- Phase 1: x window (float4) -> bf16 LDS [t][c] swizzled ----
  {
    #pragma unroll
    for (int it = 0; it < 8; ++it) {
      const int f = tid + 256 * it;
      const int c    = f >> 4;
      const int rr   = (f >> 1) & 7;
      const int half = f & 1;
      const int gh = (hb + rr) & 255;
      const int gw = (wb + 4 * half) & 255;
      const f32x4 v = *(const f32x4*)(x + (((b * 128 + c) << 16) + (gh << 8) + gw));
      const int t0 = rr * 8 + 4 * half;
      #pragma unroll
      for (int e = 0; e < 4; ++e) {
        const int t = t0 + e;
        *(unsigned short*)(sm + t * 256 + ((2 * c) ^ SW(t))) = f2bf(v[e]);
      }
    }
  }
  __syncthreads();

  const int ktc = wv * 16 + lr;
  const int ki = ktc >> 3, kj = ktc & 7;
  int boff[4][4];
  #pragma unroll
  for (int mt = 0; mt < 4; ++mt)
    #pragma unroll
    for (int r = 0; r < 4; ++r) {
      const int qrow = mt * 16 + 4 * lg + r;
      boff[mt][r] = (((qrow >> 3) - ki + 7) * 15 + ((qrow & 7) - kj + 7)) * 4;
    }

  f32x4 accpv[8];
  #pragma unroll
  for (int z = 0; z < 8; ++z) accpv[z] = (f32x4)(0.f);

  auto ldx = [&](int t, int kk) -> short8 {
    return *(const short8*)(sm + t * 256 + ((64 * kk + 16 * lg) ^ SW(t)));
  };
  auto ldw8 = [&](int row, int kk) -> short8 {
    return *(const short8*)(wbf + row * 128 + kk * 32 + 8 * lg);
  };

  // q/k sub-GEMM for head hh (verbatim R2 part 1)
  auto qkgemm = [&](int hh) {
    const int prow0 = ((wv < 2) ? 32 * hh : 128 + 32 * hh) + 16 * (wv & 1);
    short8 Af[4];
    #pragma unroll
    for (int kk = 0; kk < 4; ++kk) Af[kk] = ldw8(prow0 + lr, kk);
    unsigned char* const dst = (wv < 2) ? smq : smk;
    #pragma unroll
    for (int nt = 0; nt < 4; ++nt) {
      const int t = nt * 16 + lr;
      f32x4 acc = (f32x4)(0.f);
      #pragma unroll
      for (int kk = 0; kk < 4; ++kk)
        acc = __builtin_amdgcn_mfma_f32_16x16x32_bf16(Af[kk], ldx(t, kk), acc, 0, 0, 0);
      if (wv < 2) { acc[0] *= SCALE_F; acc[1] *= SCALE_F; acc[2] *= SCALE_F; acc[3] *= SCALE_F; }
      st_pk4(dst + t * 80 + 32 * (wv & 1) + 8 * lg, acc);
    }
  };
  // v sub-GEMM for head hh (verbatim R2 part 2)
  auto vgemm = [&](int hh) {
    const int vrow0 = 256 + 32 * hh + 16 * (wv >> 1);
    short8 Av[4];
    #pragma unroll
    for (int kk = 0; kk < 4; ++kk) Av[kk] = ldw8(vrow0 + lr, kk);
    #pragma unroll
    for (int ntl = 0; ntl < 2; ++ntl) {
      const int t = (2 * (wv & 1) + ntl) * 16 + lr;
      f32x4 acc = (f32x4)(0.f);
      #pragma unroll
      for (int kk = 0; kk < 4; ++kk)
        acc = __builtin_amdgcn_mfma_f32_16x16x32_bf16(Av[kk], ldx(t, kk), acc, 0, 0, 0);
      const int cb = 16 * (wv >> 1) + 4 * lg;
      #pragma unroll
      for (int r = 0; r < 4; ++r)
        *(unsigned short*)(smv + (cb + r) * 144 + 2 * t) = f2bf(acc[r]);
    }
  };

  // prologue: q,k for head 0
  qkgemm(0);
  __syncthreads();

  #pragma unroll 1
  for (int h = 0; h < 4; ++h) {
    // ---- phase A: vGEMM(h) || QK^T(h) (+bias +mask) -> S ----
    vgemm(h);
    {
      const short8 kb = *(const short8*)(smk + ktc * 80 + 16 * lg);
      #pragma unroll
      for (int mt = 0; mt < 4; ++mt) {
        const short8 qa = *(const short8*)(smq + (mt * 16 + lr) * 80 + 16 * lg);
        const f32x4 s = __builtin_amdgcn_mfma_f32_16x16x32_bf16(qa, kb, (f32x4)(0.f), 0, 0, 0);
        #pragma unroll
        for (int r = 0; r < 4; ++r) {
          const int qrow = mt * 16 + 4 * lg + r;
          float val = s[r] + btab[boff[mt][r] + h];
          if (h31 | w31) {
            const int qi = qrow >> 3, qj = qrow & 7;
            const bool bad = (h31 && ((qi >= 4) != (ki >= 4))) ||
                             (w31 && ((qj >= 4) != (kj >= 4)));
            val += bad ? -100.f : 0.f;
          }
          *(unsigned short*)(smS + qrow * 128 + ((2 * ktc) ^ SW(qrow))) = f2bf(val);
        }
      }
    }
    __syncthreads();

    // ---- phase B: softmax, 4 lanes/row, in-place S->P ----
    {
      const int srow = tid >> 2, sq = tid & 3;
      unsigned char* const rp = smS + srow * 128;
      const int o0 = (32 * sq) ^ SW(srow);
      const int o1 = (32 * sq + 16) ^ SW(srow);
      const short8 s0 = *(const short8*)(rp + o0);
      const short8 s1 = *(const short8*)(rp + o1);
      float v[16];
      #pragma unroll
      for (int e = 0; e < 8; ++e) { v[e] = bf2f((unsigned short)s0[e]); v[e + 8] = bf2f((unsigned short)s1[e]); }
      float mx = v[0];
      #pragma unroll
      for (int e = 1; e < 16; ++e) mx = fmaxf(mx, v[e]);
      mx = fmaxf(mx, __shfl_xor(mx, 1));
      mx = fmaxf(mx, __shfl_xor(mx, 2));
      float sum = 0.f;
      #pragma unroll
      for (int e = 0; e < 16; ++e) { v[e] = __expf(v[e] - mx); sum += v[e]; }
      sum += __shfl_xor(sum, 1);
      sum += __shfl_xor(sum, 2);
      const float inv = 1.f / sum;
      uint4v w0, w1;
      w0.x = cvtpk(v[0] * inv, v[1] * inv);  w0.y = cvtpk(v[2] * inv, v[3] * inv);
      w0.z = cvtpk(v[4] * inv, v[5] * inv);  w0.w = cvtpk(v[6] * inv, v[7] * inv);
      w1.x = cvtpk(v[8] * inv, v[9] * inv);  w1.y = cvtpk(v[10] * inv, v[11] * inv);
      w1.z = cvtpk(v[12] * inv, v[13] * inv); w1.w = cvtpk(v[14] * inv, v[15] * inv);
      *(uint4v*)(rp + o0) = w0;
      *(uint4v*)(rp + o1) = w1;
    }
    __syncthreads();

    // ---- phase C: PV(h) || qkGEMM(h+1) ----
    if (h < 3) qkgemm(h + 1);
    {
      const int q = wv * 16 + lr;
      const short8 pa0 = *(const short8*)(smS + q * 128 + ((16 * lg) ^ SW(q)));
      const short8 pa1 = *(const short8*)(smS + q * 128 + ((64 + 16 * lg) ^ SW(q)));
      #pragma unroll
      for (int nd = 0; nd < 2; ++nd) {
        const int c = nd * 16 + lr;
        const short8 vb0 = *(const short8*)(smv + c * 144 + 16 * lg);
        const short8 vb1 = *(const short8*)(smv + c * 144 + 64 + 16 * lg);
        f32x4 a = accpv[2 * h + nd];
        a = __builtin_amdgcn_mfma_f32_16x16x32_bf16(pa0, vb0, a, 0, 0, 0);
        a = __builtin_amdgcn_mfma_f32_16x16x32_bf16(pa1, vb1, a, 0, 0, 0);
        accpv[2 * h + nd] = a;
      }
    }
    __syncthreads();
  }

  // ---- attn-out -> LDS x region (x fully consumed) ----
  {
    #pragma unroll
    for (int h = 0; h < 4; ++h)
      #pragma unroll
      for (int nd = 0; nd < 2; ++nd) {
        const int c = 32 * h + nd * 16 + lr;
        const f32x4 a = accpv[2 * h + nd];
        #pragma unroll
        for (int r = 0; r < 4; ++r) {
          const int t = wv * 16 + 4 * lg + r;
          *(unsigned short*)(sm + t * 256 + ((2 * c) ^ SW(t))) = f2bf(a[r]);
        }
      }
  }
  __syncthreads();

  // ---- proj (D[t][o]) + bias -> scratch [win][mt][o][16t] (contiguous) ----
  {
    short8 Aa[16];
    #pragma unroll
    for (int mt = 0; mt < 4; ++mt)
      #pragma unroll
      for (int kk = 0; kk < 4; ++kk) {
        const int t = mt * 16 + lr;
        Aa[mt * 4 + kk] = *(const short8*)(sm + t * 256 + ((64 * kk + 16 * lg) ^ SW(t)));
      }
    #pragma unroll
    for (int ntl = 0; ntl < 2; ++ntl) {
      const int o = (wv + 4 * ntl) * 16 + lr;
      const float pb = pbH[ntl];
      #pragma unroll
      for (int mt = 0; mt < 4; ++mt) {
        f32x4 acc = (f32x4)(0.f);
        #pragma unroll
        for (int kk = 0; kk < 4; ++kk)
          acc = __builtin_amdgcn_mfma_f32_16x16x32_bf16(Aa[mt * 4 + kk], BwH[ntl][kk], acc, 0, 0, 0);
        // lanes: o consecutive (32B rows), lg = 8B quad within row -> 512B/instr
        uint2 u;
        u.x = cvtpk(acc[0] + pb, acc[1] + pb);
        u.y = cvtpk(acc[2] + pb, acc[3] + pb);
        *(uint2*)(scr + ((((win * 4 + mt) * 128) + o) << 4) + 4 * lg) = u;
      }
    }
  }
}

// ===========================================================================
// K2: scratch bf16 [win][mt][o][16t] -> out fp32 with roll(+4,+4).
// ===========================================================================
__global__ void __launch_bounds__(256, 8)
swin_k2(const unsigned short* __restrict__ scr, float* __restrict__ out)
{
  const int bid = blockIdx.x;
  const int b = bid >> 12, whp = (bid >> 7) & 31, o = bid & 127;
  const int tid = threadIdx.x;
  const int gl = tid >> 5, l32 = tid & 31;      // gl: row-in-window (t octet); l32: ww'
  const int win = b * 1024 + whp * 32 + l32;
  const short8 u = *(const short8*)(scr + ((((win * 4 + (gl >> 1)) * 128) + o) << 4) + 8 * (gl & 1));
  const int gh = (whp * 8 + 4 + gl) & 255;
  float* const orow = out + (((b * 128 + o) << 16) + (gh << 8));
  f32x4 v0, v1;
  #pragma unroll
  for (int e = 0; e < 4; ++e) { v0[e] = bf2f((unsigned short)u[e]); v1[e] = bf2f((unsigned short)u[e + 4]); }
  const int gw0 = 8 * l32 + 4;
  *(f32x4*)(orow + gw0) = v0;
  *(f32x4*)(orow + ((gw0 + 4) & 255)) = v1;     // wraps only for l32 == 31
}

// ===========================================================================
// Fallback: proven R4 single fused kernel.
// ===========================================================================
template<bool WSB>
__global__ void __launch_bounds__(256, 2)
swin_fused(const float* __restrict__ x, const float* __restrict__ qkvw_f,
           const float* __restrict__ projw_f, const float* __restrict__ projb,
           const float* __restrict__ btab, const unsigned short* __restrict__ wbf,
           float* __restrict__ out)
{
  __shared__ __align__(16) unsigned char sm[65536];
  const int tid  = threadIdx.x;
  const int lane = tid & 63, wv = tid >> 6;
  const int lr = lane & 15, lg = lane >> 4;

  const int bid = blockIdx.x;
  const int sw  = ((bid & 7) << 10) | (bid >> 3);
  const int b   = sw >> 10;
  const int wh  = (sw >> 5) & 31, ww = sw & 31;
  const int hb  = wh * 8 + 4, wb = ww * 8 + 4;
  const bool h31 = (wh == 31), w31 = (ww == 31);

  short8 BwH[2][4];
  float pbH[2];
  #pragma unroll
  for (int ntl = 0; ntl < 2; ++ntl) {
    const int o = (wv + 4 * ntl) * 16 + lr;
    pbH[ntl] = projb[o];
    #pragma unroll
    for (int kk = 0; kk < 4; ++kk) {
      const int off = o * 128 + kk * 32 + 8 * lg;
      if constexpr (WSB) {
        BwH[ntl][kk] = *(const short8*)(wbf + 49152 + off);
      } else {
        const float* p = projw_f + off;
        short8 r;
        #pragma unroll
        for (int e = 0; e < 8; ++e) r[e] = (short)f2bf(p[e]);
        BwH[ntl][kk] = r;
      }
    }
  }

  {
    #pragma unroll
    for (int it = 0; it < 8; ++it) {
      const int f = tid + 256 * it;
      const int c    = f >> 4;
      const int rr   = (f >> 1) & 7;
      const int half = f & 1;
      const int gh = (hb + rr) & 255;
      const int gw = (wb + 4 * half) & 255;
      const f32x4 v = *(const f32x4*)(x + (((b * 128 + c) << 16) + (gh << 8) + gw));
      const int t0 = rr * 8 + 4 * half;
      #pragma unroll
      for (int e = 0; e < 4; ++e) {
        const int t = t0 + e;
        *(unsigned short*)(sm + t * 256 + ((2 * c) ^ SW(t))) = f2bf(v[e]);
      }
    }
  }
  __syncthreads();

  {
    short8 Bf[16];
    #pragma unroll
    for (int nt = 0; nt < 4; ++nt)
      #pragma unroll
      for (int kk = 0; kk < 4; ++kk) {
        const int t = nt * 16 + lr;
        Bf[nt * 4 + kk] = *(short8*)(sm + t * 256 + ((64 * kk + 16 * lg) ^ SW(t)));
      }
    #pragma unroll
    for (int jj = 0; jj < 6; ++jj) {
      const int mt = wv + 4 * jj;
      const int orow = mt * 16 + lr;
      short8 Af[4];
      #pragma unroll
      for (int kk = 0; kk < 4; ++kk) {
        const int off = orow * 128 + kk * 32 + 8 * lg;
        if constexpr (WSB) {
          Af[kk] = *(const short8*)(wbf + off);
        } else {
          const float* p = qkvw_f + off;
          short8 r;
          #pragma unroll
          for (int e = 0; e < 8; ++e) r[e] = (short)f2bf(p[e]);
          Af[kk] = r;
        }
      }
      f32x4 acc[4];
      #pragma unroll
      for (int nt = 0; nt < 4; ++nt) {
        acc[nt] = (f32x4)(0.f);
        #pragma unroll
        for (int kk = 0; kk < 4; ++kk)
          acc[nt] = __builtin_amdgcn_mfma_f32_16x16x32_bf16(Af[kk], Bf[nt * 4 + kk], acc[nt], 0, 0, 0);
      }
      if (mt < 16) {
        const int base = (mt < 8) ? 16384 : 32768;
        const int c0 = ((mt & 7) * 16) + 4 * lg;
        #pragma unroll
        for (int nt = 0; nt < 4; ++nt) {
          const int t = nt * 16 + lr;
          ushort4v pk;
          #pragma unroll
          for (int r = 0; r < 4; ++r) pk[r] = f2bf(acc[nt][r]);
          *(ushort4v*)(sm + base + t * 256 + ((2 * c0) ^ SW(t))) = pk;
        }
      } else {
        const int c0 = (mt - 16) * 16 + 4 * lg;
        #pragma unroll
        for (int nt = 0; nt < 4; ++nt) {
          const int t = nt * 16 + lr;
          #pragma unroll
          for (int r = 0; r < 4; ++r) {
            const int c = c0 + r;
            *(unsigned short*)(sm + 49152 + c * 128 + ((2 * t) ^ SW(c))) = f2bf(acc[nt][r]);
          }
        }
      }
    }
  }
  __syncthreads();

  const int ktc = wv * 16 + lr;
  const int ki = ktc >> 3, kj = ktc & 7;
  int boff[4][4];
  #pragma unroll
  for (int mt = 0; mt < 4; ++mt)
    #pragma unroll
    for (int r = 0; r < 4; ++r) {
      const int qrow = mt * 16 + 4 * lg + r;
      boff[mt][r] = (((qrow >> 3) - ki + 7) * 15 + ((qrow & 7) - kj + 7)) * 4;
    }

  f32x4 accpv[8];
  #pragma unroll
  for (int z = 0; z < 8; ++z) accpv[z] = (f32x4)(0.f);

  #pragma unroll 1
  for (int h = 0; h < 4; ++h) {
    {
      const int cb = 64 * h + 16 * lg;
      const short8 kb = *(short8*)(sm + 32768 + ktc * 256 + (cb ^ SW(ktc)));
      #pragma unroll
      for (int mt = 0; mt < 4; ++mt) {
        const int q = mt * 16 + lr;
        const short8 qa = *(short8*)(sm + 16384 + q * 256 + (cb ^ SW(q)));
        f32x4 sacc = __builtin_amdgcn_mfma_f32_16x16x32_bf16(qa, kb, (f32x4)(0.f), 0, 0, 0);
        #pragma unroll
        for (int r = 0; r < 4; ++r) {
          const int qrow = mt * 16 + 4 * lg + r;
          float s = sacc[r] * SCALE_F;
          s += btab[boff[mt][r] + h];
          if (h31 | w31) {
            const int qi = qrow >> 3, qj = qrow & 7;
            const bool bad = (h31 && ((qi >= 4) != (ki >= 4))) ||
                             (w31 && ((qj >= 4) != (kj >= 4)));
            s += bad ? -100.f : 0.f;
          }
          *(unsigned short*)(sm + qrow * 128 + ((2 * ktc) ^ SW(qrow))) = f2bf(s);
        }
      }
    }
    __syncthreads();
    {
      const int srow = tid >> 2, sq = tid & 3;
      const int swz = SW(srow);
      const short8 s0 = *(short8*)(sm + srow * 128 + ((sq * 32) ^ swz));
      const short8 s1 = *(short8*)(sm + srow * 128 + ((sq * 32 + 16) ^ swz));
      float v[16];
      #pragma unroll
      for (int e = 0; e < 8; ++e) { v[e] = bf2f((unsigned short)s0[e]); v[e + 8] = bf2f((unsigned short)s1[e]); }
      float mx = v[0];
      #pragma unroll
      for (int e = 1; e < 16; ++e) mx = fmaxf(mx, v[e]);
      mx = fmaxf(mx, __shfl_xor(mx, 1));
      mx = fmaxf(mx, __shfl_xor(mx, 2));
      float sum = 0.f;
      #pragma unroll
      for (int e = 0; e < 16; ++e) { v[e] = __expf(v[e] - mx); sum += v[e]; }
      sum += __shfl_xor(sum, 1);
      sum += __shfl_xor(sum, 2);
      const float inv = 1.f / sum;
      short8 p0, p1;
      #pragma unroll
      for (int e = 0; e < 8; ++e) { p0[e] = (short)f2bf(v[e] * inv); p1[e] = (short)f2bf(v[e + 8] * inv); }
      *(short8*)(sm + 8192 + srow * 128 + ((sq * 32) ^ swz)) = p0;
      *(short8*)(sm + 8192 + srow * 128 + ((sq * 32 + 16) ^ swz)) = p1;
    }
    __syncthreads();
    {
      const int q = wv * 16 + lr;
      const short8 pa0 = *(short8*)(sm + 8192 + q * 128 + ((16 * lg) ^ SW(q)));
      const short8 pa1 = *(short8*)(sm + 8192 + q * 128 + ((64 + 16 * lg) ^ SW(q)));
      #pragma unroll
      for (int nd = 0; nd < 2; ++nd) {
        const int c = h * 32 + nd * 16 + lr;
        const short8 vb0 = *(short8*)(sm + 49152 + c * 128 + ((16 * lg) ^ SW(c)));
        const short8 vb1 = *(short8*)(sm + 49152 + c * 128 + ((64 + 16 * lg) ^ SW(c)));
        f32x4 a = accpv[h * 2 + nd];
        a = __builtin_amdgcn_mfma_f32_16x16x32_bf16(pa0, vb0, a, 0, 0, 0);
        a = __builtin_amdgcn_mfma_f32_16x16x32_bf16(pa1, vb1, a, 0, 0, 0);
        accpv[h * 2 + nd] = a;
      }
    }
  }

  {
    #pragma unroll
    for (int h = 0; h < 4; ++h)
      #pragma unroll
      for (int nd = 0; nd < 2; ++nd) {
        const int c = h * 32 + nd * 16 + lr;
        const f32x4 a = accpv[h * 2 + nd];
        #pragma unroll
        for (int r = 0; r < 4; ++r) {
          const int t = wv * 16 + 4 * lg + r;
          *(unsigned short*)(sm + 16384 + t * 256 + ((2 * c) ^ SW(t))) = f2bf(a[r]);
        }
      }
  }
  __syncthreads();

  {
    short8 Aa[16];
    #pragma unroll
    for (int mt = 0; mt < 4; ++mt)
      #pragma unroll
      for (int kk = 0; kk < 4; ++kk) {
        const int t = mt * 16 + lr;
        Aa[mt * 4 + kk] = *(short8*)(sm + 16384 + t * 256 + ((64 * kk + 16 * lg) ^ SW(t)));
      }
    #pragma unroll
    for (int ntl = 0; ntl < 2; ++ntl) {
      const int o = (wv + 4 * ntl) * 16 + lr;
      const float pb = pbH[ntl];
      #pragma unroll
      for (int mt = 0; mt < 4; ++mt) {
        f32x4 acc = (f32x4)(0.f);
        #pragma unroll
        for (int kk = 0; kk < 4; ++kk)
          acc = __builtin_amdgcn_mfma_f32_16x16x32_bf16(Aa[mt * 4 + kk], BwH[ntl][kk], acc, 0, 0, 0);
        const int t0 = mt * 16 + 4 * lg;
        const int gh = (hb + (t0 >> 3)) & 255;
        const int gw0 = (wb + (t0 & 7)) & 255;
        f32x4 ov;
        ov[0] = acc[0] + pb; ov[1] = acc[1] + pb; ov[2] = acc[2] + pb; ov[3] = acc[3] + pb;
        *(f32x4*)(out + (((b * 128 + o) << 16) + (gh << 8) + gw0)) = ov;
      }
    }
  }
}

extern "C" void kernel_launch(void* const* d_in, const int* in_sizes, int n_in,
                              void* d_out, int out_size, void* d_ws, size_t ws_size,
                              hipStream_t stream) {
  const float* x     = (const float*)d_in[0];
  const float* qkvw  = (const float*)d_in[1];
  const float* projw = (const float*)d_in[2];
  const float* projb = (const float*)d_in[3];
  const float* btab  = (const float*)d_in[4];
  float* out = (float*)d_out;

  const size_t need_split = 131072u + (size_t)8192 * 8192 * 2;  // weights + scratch
  if (ws_size >= need_split) {
    unsigned short* wsb = (unsigned short*)d_ws;
    unsigned short* scr = wsb + 65536;
    prep_weights<<<64, 256, 0, stream>>>(qkvw, projw, wsb);
    swin_k1<<<8192, 256, 0, stream>>>(x, projb, btab, wsb, scr);
    swin_k2<<<32768, 256, 0, stream>>>(scr, out);
  } else if (ws_size >= 131072) {
    unsigned short* wsb = (unsigned short*)d_ws;
    prep_weights<<<64, 256, 0, stream>>>(qkvw, projw, wsb);
    swin_fused<true><<<8192, 256, 0, stream>>>(x, qkvw, projw, projb, btab, wsb, out);
  } else {
    swin_fused<false><<<8192, 256, 0, stream>>>(x, qkvw, projw, projb, btab, nullptr, out);
  }
}

// Round 8
// 559.103 us; speedup vs baseline: 1.1468x; 1.1468x over previous
//
#include <hip/hip_runtime.h>

typedef __attribute__((ext_vector_type(8))) short short8;
typedef __attribute__((ext_vector_type(4))) unsigned short ushort4v;
typedef __attribute__((ext_vector_type(4))) float f32x4;

#define SCALE_F 0.17677669529663687f  // 1/sqrt(32)
#define SW(t) (((t) & 7) << 4)        // R1-champion swizzle

__device__ __forceinline__ unsigned short f2bf(float f){
  unsigned u = __builtin_bit_cast(unsigned, f);
  u += 0x7fffu + ((u >> 16) & 1u);          // RNE
  return (unsigned short)(u >> 16);
}
__device__ __forceinline__ float bf2f(unsigned short h){
  unsigned u = ((unsigned)h) << 16;
  return __builtin_bit_cast(float, u);
}

// One-time weight fp32 -> bf16 into workspace.
__global__ void prep_weights(const float* __restrict__ qw, const float* __restrict__ pw,
                             unsigned short* __restrict__ wsb)
{
  const int i = blockIdx.x * 256 + threadIdx.x;
  const int idx = i * 4;                        // 65536 elements total
  const float* src = (idx < 49152) ? (qw + idx) : (pw + (idx - 49152));
  f32x4 v = *(const f32x4*)src;
  ushort4v o;
  #pragma unroll
  for (int e = 0; e < 4; ++e) o[e] = f2bf(v[e]);
  *(ushort4v*)(wsb + idx) = o;
}

// One-time bias expansion: btab[(2W-1)^2, NH] -> bias_bf16[h][q][k] (32 KB).
// Kills the 64 divergent gathers/thread in the hot kernel.
__global__ void prep_bias(const float* __restrict__ btab, unsigned short* __restrict__ biasb)
{
  const int idx = blockIdx.x * 256 + threadIdx.x;   // 0..16383
  const int h = idx >> 12, q = (idx >> 6) & 63, k = idx & 63;
  const int rpi = ((q >> 3) - (k >> 3) + 7) * 15 + ((q & 7) - (k & 7) + 7);
  biasb[idx] = f2bf(btab[rpi * 4 + h]);
}

// ---------------------------------------------------------------------------
// LDS map (64 KiB -> 2 blocks/CU), R1-champion layout:
//   [    0,16384) : x bf16 [t=64][c=128] swz SW(t); ph3: S (0..8K) / P (8K..16K)
//   [16384,32768) : q bf16 [t=64][c=128] swz -> ph4+: attn-out
//   [32768,49152) : k bf16 [t=64][c=128] swz
//   [49152,65536) : vT bf16 [c=128][t=64] swz SW(c)
// ---------------------------------------------------------------------------
template<bool WSB>
__global__ void __launch_bounds__(256, 2)
swin_fused(const float* __restrict__ x, const float* __restrict__ qkvw_f,
           const float* __restrict__ projw_f, const float* __restrict__ projb,
           const float* __restrict__ btab, const unsigned short* __restrict__ wbf,
           float* __restrict__ out)
{
  __shared__ __align__(16) unsigned char sm[65536];
  const int tid  = threadIdx.x;
  const int lane = tid & 63, wv = tid >> 6;
  const int lr = lane & 15, lg = lane >> 4;

  const int bid = blockIdx.x;
  const int sw  = ((bid & 7) << 10) | (bid >> 3);
  const int b   = sw >> 10;
  const int wh  = (sw >> 5) & 31, ww = sw & 31;
  const int hb  = wh * 8 + 4, wb = ww * 8 + 4;   // roll(-4): shifted -> source
  const bool h31 = (wh == 31), w31 = (ww == 31);

  // ---- Phase 1: load x window (float4, roll -4,-4) -> bf16 LDS swizzled ----
  {
    #pragma unroll
    for (int it = 0; it < 8; ++it) {
      const int f = tid + 256 * it;          // 0..2047 float4-units
      const int c    = f >> 4;
      const int rr   = (f >> 1) & 7;
      const int half = f & 1;
      const int gh = (hb + rr) & 255;
      const int gw = (wb + 4 * half) & 255;  // 16B aligned, no intra-wrap
      const f32x4 v = *(const f32x4*)(x + (((b * 128 + c) << 16) + (gh << 8) + gw));
      const int t0 = rr * 8 + 4 * half;
      #pragma unroll
      for (int e = 0; e < 4; ++e) {
        const int t = t0 + e;
        *(unsigned short*)(sm + t * 256 + ((2 * c) ^ SW(t))) = f2bf(v[e]);
      }
    }
  }
  __syncthreads();

  // ---- Phase 2: QKV = W * x^T  (D[o][t]; M=o 24 tiles, N=t 4, K=c 4) ----
  {
    short8 Bf[16];                      // x^T fragments, reused by all o-tiles
    #pragma unroll
    for (int nt = 0; nt < 4; ++nt)
      #pragma unroll
      for (int kk = 0; kk < 4; ++kk) {
        const int t = nt * 16 + lr;
        Bf[nt * 4 + kk] = *(short8*)(sm + t * 256 + ((64 * kk + 16 * lg) ^ SW(t)));
      }
    #pragma unroll
    for (int jj = 0; jj < 6; ++jj) {
      const int mt = wv + 4 * jj;       // wave gets o-tiles {wv, wv+4, ...}
      const int orow = mt * 16 + lr;
      short8 Af[4];
      #pragma unroll
      for (int kk = 0; kk < 4; ++kk) {
        const int off = orow * 128 + kk * 32 + 8 * lg;
        if constexpr (WSB) {
          Af[kk] = *(const short8*)(wbf + off);
        } else {
          const float* p = qkvw_f + off;
          short8 r;
          #pragma unroll
          for (int e = 0; e < 8; ++e) r[e] = (short)f2bf(p[e]);
          Af[kk] = r;
        }
      }
      f32x4 acc[4];
      #pragma unroll
      for (int nt = 0; nt < 4; ++nt) {
        acc[nt] = (f32x4)(0.f);
        #pragma unroll
        for (int kk = 0; kk < 4; ++kk)
          acc[nt] = __builtin_amdgcn_mfma_f32_16x16x32_bf16(Af[kk], Bf[nt * 4 + kk], acc[nt], 0, 0, 0);
      }
      if (mt < 16) {                    // q or k: pack 4 consecutive channels
        const int base = (mt < 8) ? 16384 : 32768;
        const int c0 = ((mt & 7) * 16) + 4 * lg;
        #pragma unroll
        for (int nt = 0; nt < 4; ++nt) {
          const int t = nt * 16 + lr;
          ushort4v pk;
          #pragma unroll
          for (int r = 0; r < 4; ++r) pk[r] = f2bf(acc[nt][r]);
          *(ushort4v*)(sm + base + t * 256 + ((2 * c0) ^ SW(t))) = pk;
        }
      } else {                          // v: store transposed vT[c][t]
        const int c0 = (mt - 16) * 16 + 4 * lg;
        #pragma unroll
        for (int nt = 0; nt < 4; ++nt) {
          const int t = nt * 16 + lr;
          #pragma unroll
          for (int r = 0; r < 4; ++r) {
            const int c = c0 + r;
            *(unsigned short*)(sm + 49152 + c * 128 + ((2 * t) ^ SW(c))) = f2bf(acc[nt][r]);
          }
        }
      }
    }
  }
  __syncthreads();

  // Per-thread constants for attention epilogues
  const int ktc = wv * 16 + lr;              // key column owned in QK
  const int ki = ktc >> 3, kj = ktc & 7;
  int boff[4][4];                            // only used on !WSB fallback
  if constexpr (!WSB) {
    #pragma unroll
    for (int mt = 0; mt < 4; ++mt)
      #pragma unroll
      for (int r = 0; r < 4; ++r) {
        const int qrow = mt * 16 + 4 * lg + r;
        boff[mt][r] = (((qrow >> 3) - ki + 7) * 15 + ((qrow & 7) - kj + 7)) * 4;
      }
  }
  const unsigned short* const biasb = WSB ? (wbf + 65536) : nullptr;

  f32x4 accpv[8];
  #pragma unroll
  for (int z = 0; z < 8; ++z) accpv[z] = (f32x4)(0.f);

  for (int h = 0; h < 4; ++h) {
    // ---- QK^T (+bias +mask) -> S ----
    {
      const int cb = 64 * h + 16 * lg;             // byte col into head-h slice
      const short8 kb = *(short8*)(sm + 32768 + ktc * 256 + (cb ^ SW(ktc)));
      #pragma unroll
      for (int mt = 0; mt < 4; ++mt) {
        const int q = mt * 16 + lr;
        const short8 qa = *(short8*)(sm + 16384 + q * 256 + (cb ^ SW(q)));
        f32x4 sacc = __builtin_amdgcn_mfma_f32_16x16x32_bf16(qa, kb, (f32x4)(0.f), 0, 0, 0);
        #pragma unroll
        for (int r = 0; r < 4; ++r) {
          const int qrow = mt * 16 + 4 * lg + r;
          float s = sacc[r] * SCALE_F;
          if constexpr (WSB) {
            s += bf2f(biasb[(h << 12) | (qrow << 6) | ktc]);  // coalesced, L1-hot
          } else {
            s += btab[boff[mt][r] + h];
          }
          if (h31 | w31) {
            const int qi = qrow >> 3, qj = qrow & 7;
            const bool bad = (h31 && ((qi >= 4) != (ki >= 4))) ||
                             (w31 && ((qj >= 4) != (kj >= 4)));
            s += bad ? -100.f : 0.f;
          }
          *(unsigned short*)(sm + qrow * 128 + ((2 * ktc) ^ SW(qrow))) = f2bf(s);
        }
      }
    }
    __syncthreads();
    // ---- softmax: 4 lanes per row, S -> P ----
    {
      const int srow = tid >> 2, sq = tid & 3;
      const int swz = SW(srow);
      const short8 s0 = *(short8*)(sm + srow * 128 + ((sq * 32) ^ swz));
      const short8 s1 = *(short8*)(sm + srow * 128 + ((sq * 32 + 16) ^ swz));
      float v[16];
      #pragma unroll
      for (int e = 0; e < 8; ++e) { v[e] = bf2f((unsigned short)s0[e]); v[e + 8] = bf2f((unsigned short)s1[e]); }
      float mx = v[0];
      #pragma unroll
      for (int e = 1; e < 16; ++e) mx = fmaxf(mx, v[e]);
      mx = fmaxf(mx, __shfl_xor(mx, 1));
      mx = fmaxf(mx, __shfl_xor(mx, 2));
      float sum = 0.f;
      #pragma unroll
      for (int e = 0; e < 16; ++e) { v[e] = __expf(v[e] - mx); sum += v[e]; }
      sum += __shfl_xor(sum, 1);
      sum += __shfl_xor(sum, 2);
      const float inv = 1.f / sum;
      short8 p0, p1;
      #pragma unroll
      for (int e = 0; e < 8; ++e) { p0[e] = (short)f2bf(v[e] * inv); p1[e] = (short)f2bf(v[e + 8] * inv); }
      *(short8*)(sm + 8192 + srow * 128 + ((sq * 32) ^ swz)) = p0;
      *(short8*)(sm + 8192 + srow * 128 + ((sq * 32 + 16) ^ swz)) = p1;
    }
    __syncthreads();
    // ---- PV: wave owns q rows [16wv,16wv+16); accumulate over heads ----
    {
      const int q = wv * 16 + lr;
      const short8 pa0 = *(short8*)(sm + 8192 + q * 128 + ((16 * lg) ^ SW(q)));
      const short8 pa1 = *(short8*)(sm + 8192 + q * 128 + ((64 + 16 * lg) ^ SW(q)));
      #pragma unroll
      for (int nd = 0; nd < 2; ++nd) {
        const int c = h * 32 + nd * 16 + lr;       // vT row = head channel
        const short8 vb0 = *(short8*)(sm + 49152 + c * 128 + ((16 * lg) ^ SW(c)));
        const short8 vb1 = *(short8*)(sm + 49152 + c * 128 + ((64 + 16 * lg) ^ SW(c)));
        f32x4 a = accpv[h * 2 + nd];
        a = __builtin_amdgcn_mfma_f32_16x16x32_bf16(pa0, vb0, a, 0, 0, 0);
        a = __builtin_amdgcn_mfma_f32_16x16x32_bf16(pa1, vb1, a, 0, 0, 0);
        accpv[h * 2 + nd] = a;
      }
    }
    // no barrier: next QK writes S (0..8K) while laggards read P (8K..16K)
  }

  // ---- Phase 4: attn-out -> LDS (overlays q region) ----
  {
    #pragma unroll
    for (int h = 0; h < 4; ++h)
      #pragma unroll
      for (int nd = 0; nd < 2; ++nd) {
        const int c = h * 32 + nd * 16 + lr;
        const f32x4 a = accpv[h * 2 + nd];
        #pragma unroll
        for (int r = 0; r < 4; ++r) {
          const int t = wv * 16 + 4 * lg + r;
          *(unsigned short*)(sm + 16384 + t * 256 + ((2 * c) ^ SW(t))) = f2bf(a[r]);
        }
      }
  }
  __syncthreads();

  // ---- Phase 5: proj (D[t][o]) + bias + store with roll(+4,+4) ----
  {
    short8 Aa[16];
    #pragma unroll
    for (int mt = 0; mt < 4; ++mt)
      #pragma unroll
      for (int kk = 0; kk < 4; ++kk) {
        const int t = mt * 16 + lr;
        Aa[mt * 4 + kk] = *(short8*)(sm + 16384 + t * 256 + ((64 * kk + 16 * lg) ^ SW(t)));
      }
    #pragma unroll
    for (int ntl = 0; ntl < 2; ++ntl) {
      const int o = (wv + 4 * ntl) * 16 + lr;
      short8 Bw[4];
      #pragma unroll
      for (int kk = 0; kk < 4; ++kk) {
        const int off = o * 128 + kk * 32 + 8 * lg;
        if constexpr (WSB) {
          Bw[kk] = *(const short8*)(wbf + 49152 + off);
        } else {
          const float* p = projw_f + off;
          short8 r;
          #pragma unroll
          for (int e = 0; e < 8; ++e) r[e] = (short)f2bf(p[e]);
          Bw[kk] = r;
        }
      }
      const float pb = projb[o];
      #pragma unroll
      for (int mt = 0; mt < 4; ++mt) {
        f32x4 acc = (f32x4)(0.f);
        #pragma unroll
        for (int kk = 0; kk < 4; ++kk)
          acc = __builtin_amdgcn_mfma_f32_16x16x32_bf16(Aa[mt * 4 + kk], Bw[kk], acc, 0, 0, 0);
        const int t0 = mt * 16 + 4 * lg;       // 4 consecutive tokens, same row
        const int gh = (hb + (t0 >> 3)) & 255;
        const int gw0 = (wb + (t0 & 7)) & 255; // mult of 4 -> aligned, no wrap
        f32x4 ov;
        ov[0] = acc[0] + pb; ov[1] = acc[1] + pb; ov[2] = acc[2] + pb; ov[3] = acc[3] + pb;
        *(f32x4*)(out + (((b * 128 + o) << 16) + (gh << 8) + gw0)) = ov;
      }
    }
  }
}

extern "C" void kernel_launch(void* const* d_in, const int* in_sizes, int n_in,
                              void* d_out, int out_size, void* d_ws, size_t ws_size,
                              hipStream_t stream) {
  const float* x     = (const float*)d_in[0];
  const float* qkvw  = (const float*)d_in[1];
  const float* projw = (const float*)d_in[2];
  const float* projb = (const float*)d_in[3];
  const float* btab  = (const float*)d_in[4];
  float* out = (float*)d_out;

  // workspace: 65536 bf16 weights (128 KB) + 16384 bf16 bias (32 KB)
  if (ws_size >= 163840) {
    unsigned short* wsb = (unsigned short*)d_ws;
    prep_weights<<<64, 256, 0, stream>>>(qkvw, projw, wsb);
    prep_bias<<<64, 256, 0, stream>>>(btab, wsb + 65536);
    swin_fused<true><<<8192, 256, 0, stream>>>(x, qkvw, projw, projb, btab, wsb, out);
  } else {
    swin_fused<false><<<8192, 256, 0, stream>>>(x, qkvw, projw, projb, btab, nullptr, out);
  }
}

// Round 9
// 458.434 us; speedup vs baseline: 1.3987x; 1.2196x over previous
//
#include <hip/hip_runtime.h>

typedef __attribute__((ext_vector_type(8))) short short8;
typedef __attribute__((ext_vector_type(4))) unsigned short ushort4v;
typedef __attribute__((ext_vector_type(4))) float f32x4;

#define SCALE_F 0.17677669529663687f  // 1/sqrt(32)
#define SW(t) (((t) & 7) << 4)        // R1-champion swizzle

__device__ __forceinline__ unsigned short f2bf(float f){
  unsigned u = __builtin_bit_cast(unsigned, f);
  u += 0x7fffu + ((u >> 16) & 1u);          // RNE
  return (unsigned short)(u >> 16);
}
__device__ __forceinline__ float bf2f(unsigned short h){
  unsigned u = ((unsigned)h) << 16;
  return __builtin_bit_cast(float, u);
}

// One-time weight fp32 -> bf16 into workspace.
__global__ void prep_weights(const float* __restrict__ qw, const float* __restrict__ pw,
                             unsigned short* __restrict__ wsb)
{
  const int i = blockIdx.x * 256 + threadIdx.x;
  const int idx = i * 4;                        // 65536 elements total
  const float* src = (idx < 49152) ? (qw + idx) : (pw + (idx - 49152));
  f32x4 v = *(const f32x4*)src;
  ushort4v o;
  #pragma unroll
  for (int e = 0; e < 4; ++e) o[e] = f2bf(v[e]);
  *(ushort4v*)(wsb + idx) = o;
}

// One-time bias expansion: btab[(2W-1)^2, NH] -> bias_bf16[h][q][k] (32 KB).
__global__ void prep_bias(const float* __restrict__ btab, unsigned short* __restrict__ biasb)
{
  const int idx = blockIdx.x * 256 + threadIdx.x;   // 0..16383
  const int h = idx >> 12, q = (idx >> 6) & 63, k = idx & 63;
  const int rpi = ((q >> 3) - (k >> 3) + 7) * 15 + ((q & 7) - (k & 7) + 7);
  biasb[idx] = f2bf(btab[rpi * 4 + h]);
}

// ---------------------------------------------------------------------------
// LDS map (64 KiB -> 2 blocks/CU), R1-champion layout (VERBATIM):
//   [    0,16384) : x bf16 [t=64][c=128] swz SW(t); ph3: S (0..8K) / P (8K..16K)
//   [16384,32768) : q bf16 [t=64][c=128] swz -> ph4+: attn-out
//   [32768,49152) : k bf16 [t=64][c=128] swz
//   [49152,65536) : vT bf16 [c=128][t=64] swz SW(c)
// Deltas vs R1: (a) bias via precomputed [h][q][k] table (coalesced loads),
// (b) all qkv/proj weight fragments hoisted to registers at kernel entry.
// Phase-1 structure (scalar global loads + b128 LDS store) is R1-verbatim:
// the float4 variants regressed via bank conflicts (R4/R8 post-mortem).
// ---------------------------------------------------------------------------
template<bool WSB>
__global__ void __launch_bounds__(256, 2)
swin_fused(const float* __restrict__ x, const float* __restrict__ qkvw_f,
           const float* __restrict__ projw_f, const float* __restrict__ projb,
           const float* __restrict__ btab, const unsigned short* __restrict__ wbf,
           float* __restrict__ out)
{
  __shared__ __align__(16) unsigned char sm[65536];
  const int tid  = threadIdx.x;
  const int lane = tid & 63, wv = tid >> 6;
  const int lr = lane & 15, lg = lane >> 4;

  const int bid = blockIdx.x;
  const int sw  = ((bid & 7) << 10) | (bid >> 3);
  const int b   = sw >> 10;
  const int wh  = (sw >> 5) & 31, ww = sw & 31;
  const int hb  = wh * 8 + 4, wb = ww * 8 + 4;   // roll(-4): shifted -> source
  const bool h31 = (wh == 31), w31 = (ww == 31);

  // ---- Hoisted weights (WSB path): issue ALL weight loads up front so L2
  //      latency hides under phase 1 + barrier. 6x4 + 2x4 short8 = 128 VGPR.
  short8 AfH[6][4];    // qkv weight A-frags for o-tiles {wv + 4*jj}
  short8 BwH[2][4];    // proj weight B-frags for o-tiles {wv, wv+4}
  float pbH[2];
  if constexpr (WSB) {
    #pragma unroll
    for (int jj = 0; jj < 6; ++jj) {
      const int orow = (wv + 4 * jj) * 16 + lr;
      #pragma unroll
      for (int kk = 0; kk < 4; ++kk)
        AfH[jj][kk] = *(const short8*)(wbf + orow * 128 + kk * 32 + 8 * lg);
    }
    #pragma unroll
    for (int ntl = 0; ntl < 2; ++ntl) {
      const int o = (wv + 4 * ntl) * 16 + lr;
      pbH[ntl] = projb[o];
      #pragma unroll
      for (int kk = 0; kk < 4; ++kk)
        BwH[ntl][kk] = *(const short8*)(wbf + 49152 + o * 128 + kk * 32 + 8 * lg);
    }
  }

  // ---- Phase 1: load x window (R1-verbatim: scalar loads, b128 store) ----
  {
    const int t  = tid & 63;
    const int gh = (hb + (t >> 3)) & 255;
    const int gw = (wb + (t & 7)) & 255;
    const float* px = x + (((b * 128) << 16) + (gh << 8) + gw);
    const int c0b = (tid >> 6) * 8;
    #pragma unroll
    for (int it = 0; it < 4; ++it) {
      const int c0 = c0b + it * 32;
      const float* p = px + (c0 << 16);
      short8 v;
      #pragma unroll
      for (int cc = 0; cc < 8; ++cc) v[cc] = (short)f2bf(p[cc << 16]);
      *(short8*)(sm + t * 256 + ((2 * c0) ^ SW(t))) = v;
    }
  }
  __syncthreads();

  // ---- Phase 2: QKV = W * x^T  (D[o][t]; M=o 24 tiles, N=t 4, K=c 4) ----
  {
    short8 Bf[16];                      // x^T fragments, reused by all o-tiles
    #pragma unroll
    for (int nt = 0; nt < 4; ++nt)
      #pragma unroll
      for (int kk = 0; kk < 4; ++kk) {
        const int t = nt * 16 + lr;
        Bf[nt * 4 + kk] = *(short8*)(sm + t * 256 + ((64 * kk + 16 * lg) ^ SW(t)));
      }
    #pragma unroll
    for (int jj = 0; jj < 6; ++jj) {
      const int mt = wv + 4 * jj;       // wave gets o-tiles {wv, wv+4, ...}
      short8 Af[4];
      if constexpr (WSB) {
        #pragma unroll
        for (int kk = 0; kk < 4; ++kk) Af[kk] = AfH[jj][kk];
      } else {
        const int orow = mt * 16 + lr;
        #pragma unroll
        for (int kk = 0; kk < 4; ++kk) {
          const float* p = qkvw_f + orow * 128 + kk * 32 + 8 * lg;
          short8 r;
          #pragma unroll
          for (int e = 0; e < 8; ++e) r[e] = (short)f2bf(p[e]);
          Af[kk] = r;
        }
      }
      f32x4 acc[4];
      #pragma unroll
      for (int nt = 0; nt < 4; ++nt) {
        acc[nt] = (f32x4)(0.f);
        #pragma unroll
        for (int kk = 0; kk < 4; ++kk)
          acc[nt] = __builtin_amdgcn_mfma_f32_16x16x32_bf16(Af[kk], Bf[nt * 4 + kk], acc[nt], 0, 0, 0);
      }
      if (mt < 16) {                    // q or k: pack 4 consecutive channels
        const int base = (mt < 8) ? 16384 : 32768;
        const int c0 = ((mt & 7) * 16) + 4 * lg;
        #pragma unroll
        for (int nt = 0; nt < 4; ++nt) {
          const int t = nt * 16 + lr;
          ushort4v pk;
          #pragma unroll
          for (int r = 0; r < 4; ++r) pk[r] = f2bf(acc[nt][r]);
          *(ushort4v*)(sm + base + t * 256 + ((2 * c0) ^ SW(t))) = pk;
        }
      } else {                          // v: store transposed vT[c][t]
        const int c0 = (mt - 16) * 16 + 4 * lg;
        #pragma unroll
        for (int nt = 0; nt < 4; ++nt) {
          const int t = nt * 16 + lr;
          #pragma unroll
          for (int r = 0; r < 4; ++r) {
            const int c = c0 + r;
            *(unsigned short*)(sm + 49152 + c * 128 + ((2 * t) ^ SW(c))) = f2bf(acc[nt][r]);
          }
        }
      }
    }
  }
  __syncthreads();

  // Per-thread constants for attention epilogues
  const int ktc = wv * 16 + lr;              // key column owned in QK
  const int ki = ktc >> 3, kj = ktc & 7;
  int boff[4][4];                            // !WSB fallback only
  if constexpr (!WSB) {
    #pragma unroll
    for (int mt = 0; mt < 4; ++mt)
      #pragma unroll
      for (int r = 0; r < 4; ++r) {
        const int qrow = mt * 16 + 4 * lg + r;
        boff[mt][r] = (((qrow >> 3) - ki + 7) * 15 + ((qrow & 7) - kj + 7)) * 4;
      }
  }
  const unsigned short* const biasb = WSB ? (wbf + 65536) : nullptr;

  f32x4 accpv[8];
  #pragma unroll
  for (int z = 0; z < 8; ++z) accpv[z] = (f32x4)(0.f);

  for (int h = 0; h < 4; ++h) {
    // ---- QK^T (+bias +mask) -> S ----
    {
      const int cb = 64 * h + 16 * lg;             // byte col into head-h slice
      const short8 kb = *(short8*)(sm + 32768 + ktc * 256 + (cb ^ SW(ktc)));
      #pragma unroll
      for (int mt = 0; mt < 4; ++mt) {
        const int q = mt * 16 + lr;
        const short8 qa = *(short8*)(sm + 16384 + q * 256 + (cb ^ SW(q)));
        f32x4 sacc = __builtin_amdgcn_mfma_f32_16x16x32_bf16(qa, kb, (f32x4)(0.f), 0, 0, 0);
        #pragma unroll
        for (int r = 0; r < 4; ++r) {
          const int qrow = mt * 16 + 4 * lg + r;
          float s = sacc[r] * SCALE_F;
          if constexpr (WSB) {
            s += bf2f(biasb[(h << 12) | (qrow << 6) | ktc]);  // coalesced, L1-hot
          } else {
            s += btab[boff[mt][r] + h];
          }
          if (h31 | w31) {
            const int qi = qrow >> 3, qj = qrow & 7;
            const bool bad = (h31 && ((qi >= 4) != (ki >= 4))) ||
                             (w31 && ((qj >= 4) != (kj >= 4)));
            s += bad ? -100.f : 0.f;
          }
          *(unsigned short*)(sm + qrow * 128 + ((2 * ktc) ^ SW(qrow))) = f2bf(s);
        }
      }
    }
    __syncthreads();
    // ---- softmax: 4 lanes per row, S -> P ----
    {
      const int srow = tid >> 2, sq = tid & 3;
      const int swz = SW(srow);
      const short8 s0 = *(short8*)(sm + srow * 128 + ((sq * 32) ^ swz));
      const short8 s1 = *(short8*)(sm + srow * 128 + ((sq * 32 + 16) ^ swz));
      float v[16];
      #pragma unroll
      for (int e = 0; e < 8; ++e) { v[e] = bf2f((unsigned short)s0[e]); v[e + 8] = bf2f((unsigned short)s1[e]); }
      float mx = v[0];
      #pragma unroll
      for (int e = 1; e < 16; ++e) mx = fmaxf(mx, v[e]);
      mx = fmaxf(mx, __shfl_xor(mx, 1));
      mx = fmaxf(mx, __shfl_xor(mx, 2));
      float sum = 0.f;
      #pragma unroll
      for (int e = 0; e < 16; ++e) { v[e] = __expf(v[e] - mx); sum += v[e]; }
      sum += __shfl_xor(sum, 1);
      sum += __shfl_xor(sum, 2);
      const float inv = 1.f / sum;
      short8 p0, p1;
      #pragma unroll
      for (int e = 0; e < 8; ++e) { p0[e] = (short)f2bf(v[e] * inv); p1[e] = (short)f2bf(v[e + 8] * inv); }
      *(short8*)(sm + 8192 + srow * 128 + ((sq * 32) ^ swz)) = p0;
      *(short8*)(sm + 8192 + srow * 128 + ((sq * 32 + 16) ^ swz)) = p1;
    }
    __syncthreads();
    // ---- PV: wave owns q rows [16wv,16wv+16); accumulate over heads ----
    {
      const int q = wv * 16 + lr;
      const short8 pa0 = *(short8*)(sm + 8192 + q * 128 + ((16 * lg) ^ SW(q)));
      const short8 pa1 = *(short8*)(sm + 8192 + q * 128 + ((64 + 16 * lg) ^ SW(q)));
      #pragma unroll
      for (int nd = 0; nd < 2; ++nd) {
        const int c = h * 32 + nd * 16 + lr;       // vT row = head channel
        const short8 vb0 = *(short8*)(sm + 49152 + c * 128 + ((16 * lg) ^ SW(c)));
        const short8 vb1 = *(short8*)(sm + 49152 + c * 128 + ((64 + 16 * lg) ^ SW(c)));
        f32x4 a = accpv[h * 2 + nd];
        a = __builtin_amdgcn_mfma_f32_16x16x32_bf16(pa0, vb0, a, 0, 0, 0);
        a = __builtin_amdgcn_mfma_f32_16x16x32_bf16(pa1, vb1, a, 0, 0, 0);
        accpv[h * 2 + nd] = a;
      }
    }
    // no barrier: next QK writes S (0..8K) while laggards read P (8K..16K)
  }

  // ---- Phase 4: attn-out -> LDS (overlays q region) ----
  {
    #pragma unroll
    for (int h = 0; h < 4; ++h)
      #pragma unroll
      for (int nd = 0; nd < 2; ++nd) {
        const int c = h * 32 + nd * 16 + lr;
        const f32x4 a = accpv[h * 2 + nd];
        #pragma unroll
        for (int r = 0; r < 4; ++r) {
          const int t = wv * 16 + 4 * lg + r;
          *(unsigned short*)(sm + 16384 + t * 256 + ((2 * c) ^ SW(t))) = f2bf(a[r]);
        }
      }
  }
  __syncthreads();

  // ---- Phase 5: proj (D[t][o]) + bias + store with roll(+4,+4) ----
  {
    short8 Aa[16];
    #pragma unroll
    for (int mt = 0; mt < 4; ++mt)
      #pragma unroll
      for (int kk = 0; kk < 4; ++kk) {
        const int t = mt * 16 + lr;
        Aa[mt * 4 + kk] = *(short8*)(sm + 16384 + t * 256 + ((64 * kk + 16 * lg) ^ SW(t)));
      }
    #pragma unroll
    for (int ntl = 0; ntl < 2; ++ntl) {
      const int o = (wv + 4 * ntl) * 16 + lr;
      short8 Bw[4];
      float pb;
      if constexpr (WSB) {
        #pragma unroll
        for (int kk = 0; kk < 4; ++kk) Bw[kk] = BwH[ntl][kk];
        pb = pbH[ntl];
      } else {
        #pragma unroll
        for (int kk = 0; kk < 4; ++kk) {
          const float* p = projw_f + o * 128 + kk * 32 + 8 * lg;
          short8 r;
          #pragma unroll
          for (int e = 0; e < 8; ++e) r[e] = (short)f2bf(p[e]);
          Bw[kk] = r;
        }
        pb = projb[o];
      }
      #pragma unroll
      for (int mt = 0; mt < 4; ++mt) {
        f32x4 acc = (f32x4)(0.f);
        #pragma unroll
        for (int kk = 0; kk < 4; ++kk)
          acc = __builtin_amdgcn_mfma_f32_16x16x32_bf16(Aa[mt * 4 + kk], Bw[kk], acc, 0, 0, 0);
        const int t0 = mt * 16 + 4 * lg;       // 4 consecutive tokens, same row
        const int gh = (hb + (t0 >> 3)) & 255;
        const int gw0 = (wb + (t0 & 7)) & 255; // mult of 4 -> aligned, no wrap
        f32x4 ov;
        ov[0] = acc[0] + pb; ov[1] = acc[1] + pb; ov[2] = acc[2] + pb; ov[3] = acc[3] + pb;
        *(f32x4*)(out + (((b * 128 + o) << 16) + (gh << 8) + gw0)) = ov;
      }
    }
  }
}

extern "C" void kernel_launch(void* const* d_in, const int* in_sizes, int n_in,
                              void* d_out, int out_size, void* d_ws, size_t ws_size,
                              hipStream_t stream) {
  const float* x     = (const float*)d_in[0];
  const float* qkvw  = (const float*)d_in[1];
  const float* projw = (const float*)d_in[2];
  const float* projb = (const float*)d_in[3];
  const float* btab  = (const float*)d_in[4];
  float* out = (float*)d_out;

  // workspace: 65536 bf16 weights (128 KB) + 16384 bf16 bias (32 KB)
  if (ws_size >= 163840) {
    unsigned short* wsb = (unsigned short*)d_ws;
    prep_weights<<<64, 256, 0, stream>>>(qkvw, projw, wsb);
    prep_bias<<<64, 256, 0, stream>>>(btab, wsb + 65536);
    swin_fused<true><<<8192, 256, 0, stream>>>(x, qkvw, projw, projb, btab, wsb, out);
  } else {
    swin_fused<false><<<8192, 256, 0, stream>>>(x, qkvw, projw, projb, btab, nullptr, out);
  }
}